// Round 12
// baseline (1231.338 us; speedup 1.0000x reference)
//
#include <hip/hip_runtime.h>
#include <cstdint>
#include <cstddef>

// ---------------- problem constants ----------------
#define N_NODES 20000
#define N_EDGES 160000
#define HIDDEN  512
#define NHEAD   8
#define HDK     64
#define NLAYER  4
#define FFDIM   2048
#define ATT_SCALE 0.125f   // 1/sqrt(64)
#define S1C 262144         // 512*512
#define S2C 1048576        // 512*2048
#define WLYR (4 * S1C + 2 * S2C)   // bf16 elems of prepped weights per layer

// ---------------- MFMA types ----------------
typedef float  f4  __attribute__((ext_vector_type(4)));
typedef short  s8v __attribute__((ext_vector_type(8)));
typedef __bf16 b8v __attribute__((ext_vector_type(8)));

template <typename V>
__device__ inline auto mfma_try(V a, V b, f4 c, int)
    -> decltype(__builtin_amdgcn_mfma_f32_16x16x32_bf16(a, b, c, 0, 0, 0)) {
  return __builtin_amdgcn_mfma_f32_16x16x32_bf16(a, b, c, 0, 0, 0);
}
template <typename V>
__device__ inline f4 mfma_try(V a, V b, f4 c, long) {
  return __builtin_amdgcn_mfma_f32_16x16x32_bf16(
      __builtin_bit_cast(b8v, a), __builtin_bit_cast(b8v, b), c, 0, 0, 0);
}
__device__ inline f4 mfma_bf16(s8v a, s8v b, f4 c) { return mfma_try(a, b, c, 0); }

__device__ __forceinline__ unsigned short f2bf(float f) {
  unsigned u = __builtin_bit_cast(unsigned, f);
  u += 0x7FFFu + ((u >> 16) & 1u);   // RNE
  return (unsigned short)(u >> 16);
}
__device__ __forceinline__ float bf2f(unsigned short u) {
  return __builtin_bit_cast(float, (unsigned)u << 16);
}

// async global->LDS, 16B per lane; LDS dest is wave-uniform base + lane*16
#define GLOAD_LDS16(gp, lp)                                                   \
  __builtin_amdgcn_global_load_lds(                                           \
      (const __attribute__((address_space(1))) void*)(gp),                    \
      (__attribute__((address_space(3))) void*)(lp), 16, 0, 0)

// ---------------- fp32 -> bf16 cast ----------------
__global__ void cast_kernel(const float* __restrict__ in, unsigned short* __restrict__ out, int n) {
  int i = blockIdx.x * blockDim.x + threadIdx.x;
  if (i < n) out[i] = f2bf(in[i]);
}

// ---------------- ALL-layer weight prep in ONE dispatch ----------------
// Emits FRAGMENT-ORDERED bf16 weights: w[((nt*(K/8)+c)*16 + r)*8 + j] = W[c*8+j][nt*16+r]
__global__ void weight_prep_kernel(const float* __restrict__ Wq, const float* __restrict__ Wk,
                                   const float* __restrict__ Wv, const float* __restrict__ Wo_,
                                   const float* __restrict__ W1, const float* __restrict__ W2,
                                   const float* __restrict__ bq, const float* __restrict__ bk,
                                   const float* __restrict__ bv,
                                   unsigned short* __restrict__ wAll, float* __restrict__ bqkvAll) {
  int l = blockIdx.x / 3078;
  int id = blockIdx.x % 3078;
  unsigned short* wqkv = wAll + (size_t)l * WLYR;
  unsigned short* wo = wqkv + 3 * S1C;
  unsigned short* w1 = wo + S1C;
  unsigned short* w2 = w1 + S2C;
  if (id >= 3072) {   // bias concat
    int i = (id - 3072) * 256 + threadIdx.y * 32 + threadIdx.x;
    float* bqkv = bqkvAll + l * 1536;
    if (i < 512) bqkv[i] = bq[l * 512 + i];
    else if (i < 1024) bqkv[i] = bk[l * 512 + i - 512];
    else if (i < 1536) bqkv[i] = bv[l * 512 + i - 1024];
    return;
  }
  const float* in; unsigned short* out; int K, N, bx, by;
  if (id < 1024) {
    int m = id >> 8, t = id & 255;
    in = ((m == 0) ? Wq : (m == 1) ? Wk : (m == 2) ? Wv : Wo_) + (size_t)l * S1C;
    out = (m == 3) ? wo : wqkv + m * S1C;
    K = 512; N = 512; bx = t & 15; by = t >> 4;
  } else if (id < 2048) {
    int t = id - 1024;
    in = W1 + (size_t)l * S2C; out = w1; K = 512; N = 2048; bx = t & 63; by = t >> 6;
  } else {
    int t = id - 2048;
    in = W2 + (size_t)l * S2C; out = w2; K = 2048; N = 512; bx = t & 15; by = t >> 4;
  }
  __shared__ float t32[32][33];
  int tx = threadIdx.x, ty = threadIdx.y;
  int n0 = bx * 32, k0 = by * 32;
  int Kc = K >> 3;
#pragma unroll
  for (int i = 0; i < 32; i += 8)
    t32[ty + i][tx] = in[(size_t)(k0 + ty + i) * N + n0 + tx];
  __syncthreads();
#pragma unroll
  for (int i = 0; i < 32; i += 8) {
    int n = n0 + ty + i, k = k0 + tx;
    size_t idx = ((size_t)(n >> 4) * Kc + (k >> 3)) * 128 + (n & 15) * 8 + (k & 7);
    out[idx] = f2bf(t32[tx][ty + i]);   // t32[tx][ty+i] = W[k][n]
  }
}

// ---------------- GEMM 128x128: big-grid dispatches (QKV, FF1) ----------------
// SPLITB=true (launch_bounds(256,4)): DOUBLE-K-TILE iteration -- each K-iter
// stages TWO independent 128x64 A-subtiles (each with the proven conflict-free
// 128B row stride; round-4's single 256B-stride tile hit 2.57M bank-conflict
// cycles) and computes 64 MFMAs between barriers. Halves the vmcnt(0)+barrier
// drain count (16 -> 8 per block at K=512). B loaded one 4-frag set at a time
// (32-VGPR peak liveness) so 4 blocks/CU still fit; the exposed B-load latency
// is covered by the 4 co-resident blocks (round-8/9: works at grids >= ~1024).
// k-accumulation order is sequential -> numerics identical.
// SPLITB=false (launch_bounds(256,3)): round-1 verbatim (kept for reference).
#define BM 128
#define BN 128
#define BK 64

template <bool OBF16, bool SPLITB>
__global__ __launch_bounds__(256, SPLITB ? 4 : 3) void gemm_bf16(
    const unsigned short* __restrict__ A, const unsigned short* __restrict__ Bt,
    const float* __restrict__ bias, void* __restrict__ Cp,
    int M, int K, int N, int relu) {
  __shared__ __align__(16) unsigned short As[SPLITB ? 16384 : 8192];
  int tid = threadIdx.x;
  int wave = tid >> 6, lane = tid & 63;
  int quad = lane >> 4, l16 = lane & 15;
  int wm = (wave >> 1) * 64, wn = (wave & 1) * 64;

  // XCD swizzle: contiguous work range per XCD
  int T = gridDim.x * gridDim.y;
  int i = blockIdx.y * gridDim.x + blockIdx.x;
  int C = T >> 3;
  int w = (i < (C << 3)) ? ((i & 7) * C + (i >> 3)) : i;
  int bx = w % gridDim.x, by = w / gridDim.x;
  int m0 = by * BM, n0 = bx * BN;

  f4 acc[4][4];
#pragma unroll
  for (int i2 = 0; i2 < 4; ++i2)
#pragma unroll
    for (int j = 0; j < 4; ++j) acc[i2][j] = (f4){0.f, 0.f, 0.f, 0.f};

  // A staging: round j covers rows [j*32, j*32+32); XOR-swizzled k-chunk
  int rbase = wave * 8 + (lane >> 3);
  int q8 = (lane & 7) ^ ((lane >> 3) & 7);
  const unsigned short* aptr[4];
#pragma unroll
  for (int j = 0; j < 4; ++j) {
    int r = j * 32 + rbase;
    int gm = m0 + r; if (gm >= M) gm = M - 1;   // clamp: dup rows never stored
    aptr[j] = A + (size_t)gm * K + q8 * 8;
  }

  // B fragment pointers: addr = (NT*(K/8) + c)*128 + l16*8
  int Kc = K >> 3;
  const unsigned short* bbase = Bt + quad * 128 + l16 * 8;
  size_t nioff[4];
#pragma unroll
  for (int i2 = 0; i2 < 4; ++i2)
    nioff[i2] = ((size_t)((n0 >> 4) + (wn >> 4) + i2) * Kc) * 128;

  if constexpr (SPLITB) {
    // double-K-tile loop: 128 k-cols per barrier pair, two 128x64 LDS tiles
    int nk = K >> 7;
    for (int ks = 0; ks < nk; ++ks) {
      const int ka = ks * 128;
#pragma unroll
      for (int j = 0; j < 4; ++j) {
        GLOAD_LDS16(aptr[j] + ka,      &As[j * 2048 + wave * 512]);
        GLOAD_LDS16(aptr[j] + ka + 64, &As[8192 + j * 2048 + wave * 512]);
      }
      s8v bfr[4];
      // B (h=0, s=0) pre-barrier; remaining 3 sets loaded between MFMA groups
#pragma unroll
      for (int i2 = 0; i2 < 4; ++i2)
        bfr[i2] = *(const s8v*)(bbase + nioff[i2] + (size_t)ks * 2048);
      __syncthreads();
#pragma unroll
      for (int h = 0; h < 2; ++h) {
#pragma unroll
        for (int s = 0; s < 2; ++s) {
          s8v af[4];
#pragma unroll
          for (int i2 = 0; i2 < 4; ++i2) {
            int ra = wm + i2 * 16 + l16;
            af[i2] = *(const s8v*)(&As[h * 8192 + ra * 64 +
                                       ((((s << 2) | quad) ^ (ra & 7)) * 8)]);
          }
#pragma unroll
          for (int mi = 0; mi < 4; ++mi)
#pragma unroll
            for (int ni = 0; ni < 4; ++ni)
              acc[mi][ni] = mfma_bf16(af[mi], bfr[ni], acc[mi][ni]);
          // load next B set (h,s order: 00 -> 01 -> 10 -> 11)
          if (h * 2 + s < 3) {
            int nh = (s == 1) ? h + 1 : h;
            int ns = (s == 1) ? 0 : 1;
#pragma unroll
            for (int i2 = 0; i2 < 4; ++i2)
              bfr[i2] = *(const s8v*)(bbase + nioff[i2] +
                                      (size_t)ks * 2048 + nh * 1024 + ns * 512);
          }
        }
      }
      __syncthreads();
    }
  } else {
    // round-1 verbatim: BK=64, both B sets pre-barrier
    int nk = K >> 6;
    for (int ks = 0; ks < nk; ++ks) {
#pragma unroll
      for (int j = 0; j < 4; ++j)
        GLOAD_LDS16(aptr[j] + ks * 64, &As[j * 2048 + wave * 512]);
      s8v bfr[2][4];
#pragma unroll
      for (int s = 0; s < 2; ++s)
#pragma unroll
        for (int i2 = 0; i2 < 4; ++i2)
          bfr[s][i2] = *(const s8v*)(bbase + nioff[i2] + (size_t)ks * 1024 + s * 512);
      __syncthreads();
#pragma unroll
      for (int s = 0; s < 2; ++s) {
        s8v af[4];
#pragma unroll
        for (int i2 = 0; i2 < 4; ++i2) {
          int ra = wm + i2 * 16 + l16;
          af[i2] = *(const s8v*)(&As[ra * 64 + ((((s << 2) | quad) ^ (ra & 7)) * 8)]);
        }
#pragma unroll
        for (int mi = 0; mi < 4; ++mi)
#pragma unroll
          for (int ni = 0; ni < 4; ++ni)
            acc[mi][ni] = mfma_bf16(af[mi], bfr[s][ni], acc[mi][ni]);
      }
      __syncthreads();
    }
  }

  if constexpr (OBF16) {
    // coalesced bf16 epilogue: restage each wave's 16x64 subtile through LDS (reuse As)
    unsigned short* Cs = As + wave * 1088;   // 16 rows x 64 cols, stride 68
    float bvv[4];
#pragma unroll
    for (int ni = 0; ni < 4; ++ni) bvv[ni] = bias[n0 + wn + ni * 16 + l16];
    int row_l = lane >> 2, cg = lane & 3;
#pragma unroll
    for (int mi = 0; mi < 4; ++mi) {
#pragma unroll
      for (int ni = 0; ni < 4; ++ni) {
#pragma unroll
        for (int r = 0; r < 4; ++r) {
          float val = acc[mi][ni][r] + bvv[ni];
          if (relu) val = fmaxf(val, 0.f);
          Cs[(quad * 4 + r) * 68 + ni * 16 + l16] = f2bf(val);
        }
      }
      s8v v0 = *(const s8v*)(&Cs[row_l * 68 + cg * 16]);
      s8v v1 = *(const s8v*)(&Cs[row_l * 68 + cg * 16 + 8]);
      int grow = m0 + wm + mi * 16 + row_l;
      if (grow < M) {
        unsigned short* cp = (unsigned short*)Cp + (size_t)grow * N + n0 + wn + cg * 16;
        *(s8v*)cp = v0;
        *(s8v*)(cp + 8) = v1;
      }
    }
  } else {
#pragma unroll
    for (int ni = 0; ni < 4; ++ni) {
      int col = n0 + wn + ni * 16 + l16;
      float bv = bias[col];
#pragma unroll
      for (int mi = 0; mi < 4; ++mi) {
#pragma unroll
        for (int r = 0; r < 4; ++r) {
          int row = m0 + wm + mi * 16 + quad * 4 + r;
          if (row < M) {
            float val = acc[mi][ni][r] + bv;
            if (relu) val = fmaxf(val, 0.f);
            ((float*)Cp)[(size_t)row * N + col] = val;
          }
        }
      }
    }
  }
}

// ---------------- GEMM 64x128: small-grid dispatches (Wo, FF2) ----------------
// BM=64 doubles the small-N grid (1252 blocks) and fits 4 blocks/CU -- round-9's
// fix for the 2.45-blocks/CU drain-coverage hole (FF2 61 -> <57us measured).
__global__ __launch_bounds__(256, 4) void gemm_sm(
    const unsigned short* __restrict__ A, const unsigned short* __restrict__ Bt,
    const float* __restrict__ bias, unsigned short* __restrict__ Cp,
    int M, int K, int N, int relu) {
  __shared__ __align__(16) unsigned short As[4096];   // 64 x 64 bf16 (8 KB)
  int tid = threadIdx.x;
  int wave = tid >> 6, lane = tid & 63;
  int quad = lane >> 4, l16 = lane & 15;
  int wn = wave * 32;                 // wave covers 64 rows x 32 cols

  // XCD swizzle
  int T = gridDim.x * gridDim.y;
  int i = blockIdx.y * gridDim.x + blockIdx.x;
  int C = T >> 3;
  int w = (i < (C << 3)) ? ((i & 7) * C + (i >> 3)) : i;
  int bx = w % gridDim.x, by = w / gridDim.x;
  int m0 = by * 64, n0 = bx * BN;

  f4 acc[4][2];
#pragma unroll
  for (int i2 = 0; i2 < 4; ++i2)
#pragma unroll
    for (int j = 0; j < 2; ++j) acc[i2][j] = (f4){0.f, 0.f, 0.f, 0.f};

  // A staging: round j covers rows [j*32, j*32+32) (same pattern as 128-tile)
  int rbase = wave * 8 + (lane >> 3);
  int q8 = (lane & 7) ^ ((lane >> 3) & 7);
  const unsigned short* aptr[2];
#pragma unroll
  for (int j = 0; j < 2; ++j) {
    int r = j * 32 + rbase;
    int gm = m0 + r; if (gm >= M) gm = M - 1;
    aptr[j] = A + (size_t)gm * K + q8 * 8;
  }

  int Kc = K >> 3;
  const unsigned short* bbase = Bt + quad * 128 + l16 * 8;
  size_t nioff[2];
#pragma unroll
  for (int i2 = 0; i2 < 2; ++i2)
    nioff[i2] = ((size_t)((n0 >> 4) + (wn >> 4) + i2) * Kc) * 128;

  int nk = K >> 6;
  for (int ks = 0; ks < nk; ++ks) {
#pragma unroll
    for (int j = 0; j < 2; ++j)
      GLOAD_LDS16(aptr[j], &As[j * 2048 + wave * 512]);
    s8v bfr[2][2];
#pragma unroll
    for (int s = 0; s < 2; ++s)
#pragma unroll
      for (int i2 = 0; i2 < 2; ++i2)
        bfr[s][i2] = *(const s8v*)(bbase + nioff[i2] + (size_t)ks * 1024 + s * 512);
#pragma unroll
    for (int j = 0; j < 2; ++j) aptr[j] += BK;
    __syncthreads();
#pragma unroll
    for (int s = 0; s < 2; ++s) {
      s8v af[4];
#pragma unroll
      for (int i2 = 0; i2 < 4; ++i2) {
        int ra = i2 * 16 + l16;
        af[i2] = *(const s8v*)(&As[ra * 64 + ((((s << 2) | quad) ^ (ra & 7)) * 8)]);
      }
#pragma unroll
      for (int mi = 0; mi < 4; ++mi)
#pragma unroll
        for (int ni = 0; ni < 2; ++ni)
          acc[mi][ni] = mfma_bf16(af[mi], bfr[s][ni], acc[mi][ni]);
    }
    __syncthreads();
  }

  // bf16 epilogue: per-wave 16x32 restage (stride 36), coalesced s8v stores
  unsigned short* Cs = As + wave * 576;
  float bvv[2];
#pragma unroll
  for (int ni = 0; ni < 2; ++ni) bvv[ni] = bias[n0 + wn + ni * 16 + l16];
  int row_l = lane >> 2, cg = lane & 3;
#pragma unroll
  for (int mi = 0; mi < 4; ++mi) {
#pragma unroll
    for (int ni = 0; ni < 2; ++ni)
#pragma unroll
      for (int r = 0; r < 4; ++r) {
        float val = acc[mi][ni][r] + bvv[ni];
        if (relu) val = fmaxf(val, 0.f);
        Cs[(quad * 4 + r) * 36 + ni * 16 + l16] = f2bf(val);
      }
    s8v v0 = *(const s8v*)(&Cs[row_l * 36 + cg * 8]);
    int grow = m0 + mi * 16 + row_l;
    if (grow < M) {
      unsigned short* cp = Cp + (size_t)grow * N + n0 + wn + cg * 8;
      *(s8v*)cp = v0;
    }
  }
}

// ---------------- CSR build ----------------
__global__ void hist_kernel(const int* __restrict__ dst, int* __restrict__ cnt, int E) {
  int e = blockIdx.x * blockDim.x + threadIdx.x;
  if (e < E) atomicAdd(&cnt[dst[e]], 1);
}

// parallel two-level scan
__global__ void scan_blk_kernel(const int* __restrict__ cnt, int* __restrict__ incl,
                                int* __restrict__ bsum, int n) {
  __shared__ int sh[1024];
  int tid = threadIdx.x;
  int gi = blockIdx.x * 1024 + tid;
  int v = (gi < n) ? cnt[gi] : 0;
  sh[tid] = v;
  __syncthreads();
  for (int s = 1; s < 1024; s <<= 1) {
    int t = (tid >= s) ? sh[tid - s] : 0;
    __syncthreads();
    sh[tid] += t;
    __syncthreads();
  }
  if (gi < n) incl[gi] = sh[tid];
  if (tid == 1023) bsum[blockIdx.x] = sh[1023];
}

__global__ void scan_mid_kernel(const int* __restrict__ bsum, int* __restrict__ boff, int nb) {
  if (threadIdx.x == 0 && blockIdx.x == 0) {
    int run = 0;
    for (int i = 0; i < nb; ++i) { boff[i] = run; run += bsum[i]; }
    boff[nb] = run;
  }
}

__global__ void scan_fix_kernel(const int* __restrict__ incl, const int* __restrict__ boff,
                                int* __restrict__ offs, int n) {
  int gi = blockIdx.x * 1024 + threadIdx.x;
  if (gi < n) offs[gi + 1] = boff[blockIdx.x] + incl[gi];
  if (gi == 0) offs[0] = 0;
}

__global__ void scatter_kernel(const int* __restrict__ dst, const int* __restrict__ src,
                               const int* __restrict__ relations, const int* __restrict__ offs,
                               int* __restrict__ cursor, int* __restrict__ esrc,
                               int* __restrict__ erel, int E) {
  int e = blockIdx.x * blockDim.x + threadIdx.x;
  if (e < E) {
    int d = dst[e];
    int pos = offs[d] + atomicAdd(&cursor[d], 1);
    esrc[pos] = src[e];
    erel[pos] = relations[e];
  }
}

// ---------------- fused edge attention: one wave per dst node, online softmax -----
// 3-deep gather pipeline with lane-parallel index preload (perf-equal to simpler
// variants -> attn is gather-BW-bound on L3, near floor; kept as verified).
#define ATT_LOAD(j, kx, vx, rx) do {                                          \
    int sj = __shfl(si_l, (j), 64);                                           \
    int rj = __shfl(ri_l, (j), 64);                                           \
    kx = *(const s8v*)(k + (size_t)sj * STR + base);                          \
    vx = *(const s8v*)(v + (size_t)sj * STR + base);                          \
    rx = *(const s8v*)(relb + (size_t)rj * HIDDEN + base);                    \
  } while (0)

#define ATT_STEP(kc, vc, rc) do {                                             \
    float rf[8], p = 0.f;                                                     \
    _Pragma("unroll") for (int jj = 0; jj < 8; ++jj) {                        \
      rf[jj] = bf2f((unsigned short)kc[jj]);                                  \
      float rr = bf2f((unsigned short)rc[jj]);                                \
      p += (rf[jj] + rr) * qf[jj];                                            \
      rf[jj] = rr;                                                            \
    }                                                                         \
    p += __shfl_xor(p, 1, 64);                                                \
    p += __shfl_xor(p, 2, 64);                                                \
    p += __shfl_xor(p, 4, 64);                                                \
    p *= ATT_SCALE;                                                           \
    float mn = fmaxf(m, p);                                                   \
    float a = __expf(m - mn);                                                 \
    float wgt = __expf(p - mn);                                               \
    z = z * a + wgt;                                                          \
    _Pragma("unroll") for (int jj = 0; jj < 8; ++jj)                          \
      acc[jj] = acc[jj] * a + wgt * (bf2f((unsigned short)vc[jj]) + rf[jj]);  \
    m = mn;                                                                   \
  } while (0)

__global__ void edge_attn_kernel(const unsigned short* __restrict__ q,
                                 const unsigned short* __restrict__ k,
                                 const unsigned short* __restrict__ v,
                                 const unsigned short* __restrict__ relb,
                                 const int* __restrict__ offs,
                                 const int* __restrict__ esrc,
                                 const int* __restrict__ erel,
                                 unsigned short* __restrict__ o, int Nn, int STR) {
  int wid = (blockIdx.x * blockDim.x + threadIdx.x) >> 6;
  int lane = threadIdx.x & 63;
  if (wid >= Nn) return;
  int base = (lane >> 3) * HDK + (lane & 7) * 8;

  s8v qv = *(const s8v*)(q + (size_t)wid * STR + base);
  float qf[8];
#pragma unroll
  for (int j = 0; j < 8; ++j) qf[j] = bf2f((unsigned short)qv[j]);

  int beg = offs[wid], end = offs[wid + 1];
  float m = -1e30f, z = 0.f;
  float acc[8];
#pragma unroll
  for (int j = 0; j < 8; ++j) acc[j] = 0.f;

  for (int cbeg = beg; cbeg < end; cbeg += 64) {
    int cn = end - cbeg; if (cn > 64) cn = 64;
    int e = cbeg + lane;
    int si_l = 0, ri_l = 0;
    if (e < end) { si_l = esrc[e]; ri_l = erel[e]; }
    s8v kA = {}, vA = {}, rA = {};
    s8v kB = {}, vB = {}, rB = {};
    s8v kC = {}, vC = {}, rC = {};
    if (cn > 0) ATT_LOAD(0, kA, vA, rA);
    if (cn > 1) ATT_LOAD(1, kB, vB, rB);
    if (cn > 2) ATT_LOAD(2, kC, vC, rC);
    int j = 0;
    for (; j + 5 < cn; j += 3) {
      ATT_STEP(kA, vA, rA); ATT_LOAD(j + 3, kA, vA, rA);
      ATT_STEP(kB, vB, rB); ATT_LOAD(j + 4, kB, vB, rB);
      ATT_STEP(kC, vC, rC); ATT_LOAD(j + 5, kC, vC, rC);
    }
    int r = cn - j;   // 1..5
    if (r >= 1) ATT_STEP(kA, vA, rA);
    if (r >= 4) ATT_LOAD(j + 3, kA, vA, rA);
    if (r >= 2) ATT_STEP(kB, vB, rB);
    if (r >= 5) ATT_LOAD(j + 4, kB, vB, rB);
    if (r >= 3) ATT_STEP(kC, vC, rC);
    if (r >= 4) ATT_STEP(kA, vA, rA);
    if (r >= 5) ATT_STEP(kB, vB, rB);
  }

  float rz = 1.f / (z + 1e-9f);
  s8v ov;
#pragma unroll
  for (int j = 0; j < 8; ++j) ov[j] = (short)f2bf(acc[j] * rz);
  *(s8v*)(o + (size_t)wid * HIDDEN + base) = ov;
}

// ---------------- fused residual add + LayerNorm (one wave per row, bf16 in) ----------------
template <bool WF32>
__global__ void ln_kernel(const unsigned short* __restrict__ xp, const unsigned short* __restrict__ y,
                          const float* __restrict__ g, const float* __restrict__ b,
                          float* __restrict__ outf, unsigned short* __restrict__ outb, int Nn) {
  int wid = (blockIdx.x * blockDim.x + threadIdx.x) >> 6;
  int lane = threadIdx.x & 63;
  if (wid >= Nn) return;
  int base = lane * 8;
  s8v xv = *(const s8v*)(xp + (size_t)wid * HIDDEN + base);
  s8v yv = *(const s8v*)(y + (size_t)wid * HIDDEN + base);
  float vals[8];
  float sum = 0.f;
#pragma unroll
  for (int j = 0; j < 8; ++j) {
    vals[j] = bf2f((unsigned short)xv[j]) + bf2f((unsigned short)yv[j]);
    sum += vals[j];
  }
#pragma unroll
  for (int off = 32; off; off >>= 1) sum += __shfl_xor(sum, off, 64);
  float mean = sum * (1.f / 512.f);
  float sq = 0.f;
#pragma unroll
  for (int j = 0; j < 8; ++j) { float d = vals[j] - mean; sq += d * d; }
#pragma unroll
  for (int off = 32; off; off >>= 1) sq += __shfl_xor(sq, off, 64);
  float rstd = rsqrtf(sq * (1.f / 512.f) + 1e-5f);
  f4 gv0 = *(const f4*)(g + base);
  f4 gv1 = *(const f4*)(g + base + 4);
  f4 bv0 = *(const f4*)(b + base);
  f4 bv1 = *(const f4*)(b + base + 4);
  float ov_f[8];
#pragma unroll
  for (int j = 0; j < 4; ++j) {
    ov_f[j]     = (vals[j]     - mean) * rstd * gv0[j] + bv0[j];
    ov_f[j + 4] = (vals[j + 4] - mean) * rstd * gv1[j] + bv1[j];
  }
  s8v ov;
#pragma unroll
  for (int j = 0; j < 8; ++j) ov[j] = (short)f2bf(ov_f[j]);
  *(s8v*)(outb + (size_t)wid * HIDDEN + base) = ov;
  if constexpr (WF32) {
    f4 o0, o1;
#pragma unroll
    for (int j = 0; j < 4; ++j) { o0[j] = ov_f[j]; o1[j] = ov_f[j + 4]; }
    *(f4*)(outf + (size_t)wid * HIDDEN + base) = o0;
    *(f4*)(outf + (size_t)wid * HIDDEN + base + 4) = o1;
  }
}

// ---------------- host orchestration ----------------
extern "C" void kernel_launch(void* const* d_in, const int* in_sizes, int n_in,
                              void* d_out, int out_size, void* d_ws, size_t ws_size,
                              hipStream_t stream) {
  const float* x0        = (const float*)d_in[0];
  const int*   relations = (const int*)d_in[1];
  const int*   src       = (const int*)d_in[2];
  const int*   dst       = (const int*)d_in[3];
  const float* rel_embed = (const float*)d_in[4];
  const float* Wq = (const float*)d_in[5];  const float* bq = (const float*)d_in[6];
  const float* Wk = (const float*)d_in[7];  const float* bk = (const float*)d_in[8];
  const float* Wv = (const float*)d_in[9];  const float* bv = (const float*)d_in[10];
  const float* Wo = (const float*)d_in[11]; const float* bo = (const float*)d_in[12];
  const float* W1 = (const float*)d_in[13]; const float* b1 = (const float*)d_in[14];
  const float* W2 = (const float*)d_in[15]; const float* b2 = (const float*)d_in[16];
  const float* g1  = (const float*)d_in[17]; const float* bb1 = (const float*)d_in[18];
  const float* g2  = (const float*)d_in[19]; const float* bb2 = (const float*)d_in[20];
  float* xout = (float*)d_out;

  const size_t S1 = S1C;
  const size_t S2 = S2C;
  const size_t NH = (size_t)N_NODES * HIDDEN;   // 10,240,000

  // ---- workspace layout (~163 MiB) ----
  unsigned short* wAll = (unsigned short*)d_ws;           // 4 * WLYR bf16
  float* bqkvAll = (float*)(wAll + (size_t)NLAYER * WLYR); // 4*1536 fp32
  unsigned short* arena = (unsigned short*)(bqkvAll + NLAYER * 1536);  // 4*NH bf16
  unsigned short* qkvb = arena;                 // 3*NH, row stride 1536
  unsigned short* ob   = arena + 3 * NH;        // NH, row stride 512
  unsigned short* ff1  = arena;                 // 4*NH (qkv/ob dead by FF1 time)
  unsigned short* proj = arena;                 // NH bf16, aliases dead qkvb at Wo time
  unsigned short* hbb = arena + 4 * NH;         // NH bf16 (LN1 out)
  unsigned short* xb  = hbb + NH;               // NH bf16 (layer input / residual)
  unsigned short* projb = xb + NH;              // NH bf16 (FF2 out)
  unsigned short* relb  = projb + NH;           // 128*512 bf16
  int* cnt    = (int*)(relb + 65536);
  int* offs   = cnt + N_NODES;
  int* cursor = offs + N_NODES + 1;
  int* esrc   = cursor + N_NODES;
  int* erel   = esrc + N_EDGES;
  int* sincl  = erel + N_EDGES;     // 20480 (per-element inclusive scans)
  int* sbsum  = sincl + 20480;      // 32
  int* sboff  = sbsum + 32;         // 33

  // ---- setup (once per call) ----
  hipMemsetAsync(cnt, 0, N_NODES * sizeof(int), stream);
  hipMemsetAsync(cursor, 0, N_NODES * sizeof(int), stream);
  hist_kernel<<<(N_EDGES + 255) / 256, 256, 0, stream>>>(dst, cnt, N_EDGES);
  const int NB = (N_NODES + 1023) / 1024;   // 20
  scan_blk_kernel<<<NB, 1024, 0, stream>>>(cnt, sincl, sbsum, N_NODES);
  scan_mid_kernel<<<1, 64, 0, stream>>>(sbsum, sboff, NB);
  scan_fix_kernel<<<NB, 1024, 0, stream>>>(sincl, sboff, offs, N_NODES);
  scatter_kernel<<<(N_EDGES + 255) / 256, 256, 0, stream>>>(dst, src, relations, offs, cursor, esrc, erel, N_EDGES);
  cast_kernel<<<(int)((NH + 255) / 256), 256, 0, stream>>>(x0, xb, (int)NH);
  cast_kernel<<<256, 256, 0, stream>>>(rel_embed, relb, 65536);
  dim3 tb(32, 8);
  weight_prep_kernel<<<NLAYER * 3078, tb, 0, stream>>>(Wq, Wk, Wv, Wo, W1, W2, bq, bk, bv,
                                                       wAll, bqkvAll);

  const int MBc = (N_NODES + BM - 1) / BM;   // 157 (128-row tiles)
  const int MBs = (N_NODES + 63) / 64;       // 313 (64-row tiles)

  for (int l = 0; l < NLAYER; ++l) {
    unsigned short* wqkv = wAll + (size_t)l * WLYR;
    unsigned short* wo = wqkv + 3 * S1;
    unsigned short* w1 = wo + S1;
    unsigned short* w2 = w1 + S2;
    float* bqkv = bqkvAll + l * 1536;
    // merged QKV projection (big grid -> double-K-tile SPLITB)
    gemm_bf16<true, true><<<dim3(12, MBc), 256, 0, stream>>>(xb, wqkv, bqkv, qkvb, N_NODES, 512, 1536, 0);
    // fused edge attention
    edge_attn_kernel<<<(N_NODES + 3) / 4, 256, 0, stream>>>(qkvb, qkvb + 512, qkvb + 1024,
                                                            relb, offs, esrc, erel, ob, N_NODES, 1536);
    // output projection (small grid -> BM=64 high-occupancy kernel), then LN1
    gemm_sm<<<dim3(4, MBs), 256, 0, stream>>>(ob, wo, bo + l * 512, proj, N_NODES, 512, 512, 0);
    ln_kernel<false><<<N_NODES / 4, 256, 0, stream>>>(xb, proj, g1 + l * 512, bb1 + l * 512, nullptr, hbb, N_NODES);
    // FFN: FF1 big grid -> double-K-tile SPLITB; FF2 small grid -> BM=64 kernel
    gemm_bf16<true, true><<<dim3(16, MBc), 256, 0, stream>>>(hbb, w1, b1 + l * 2048, ff1, N_NODES, 512, 2048, 1);
    gemm_sm<<<dim3(4, MBs), 256, 0, stream>>>(ff1, w2, b2 + l * 512, projb, N_NODES, 2048, 512, 0);
    // LN2 -> xb (bf16 next-layer input/residual); final layer also writes fp32 xout
    if (l == NLAYER - 1)
      ln_kernel<true><<<N_NODES / 4, 256, 0, stream>>>(hbb, projb, g2 + l * 512, bb2 + l * 512, xout, xb, N_NODES);
    else
      ln_kernel<false><<<N_NODES / 4, 256, 0, stream>>>(hbb, projb, g2 + l * 512, bb2 + l * 512, nullptr, xb, N_NODES);
  }
}

// Round 13
// 1161.606 us; speedup vs baseline: 1.0600x; 1.0600x over previous
//
#include <hip/hip_runtime.h>
#include <cstdint>
#include <cstddef>

// ---------------- problem constants ----------------
#define N_NODES 20000
#define N_EDGES 160000
#define HIDDEN  512
#define NHEAD   8
#define HDK     64
#define NLAYER  4
#define FFDIM   2048
#define ATT_SCALE 0.125f   // 1/sqrt(64)
#define S1C 262144         // 512*512
#define S2C 1048576        // 512*2048
#define WLYR (4 * S1C + 2 * S2C)   // bf16 elems of prepped weights per layer

// ---------------- MFMA types ----------------
typedef float  f4  __attribute__((ext_vector_type(4)));
typedef short  s8v __attribute__((ext_vector_type(8)));
typedef __bf16 b8v __attribute__((ext_vector_type(8)));

template <typename V>
__device__ inline auto mfma_try(V a, V b, f4 c, int)
    -> decltype(__builtin_amdgcn_mfma_f32_16x16x32_bf16(a, b, c, 0, 0, 0)) {
  return __builtin_amdgcn_mfma_f32_16x16x32_bf16(a, b, c, 0, 0, 0);
}
template <typename V>
__device__ inline f4 mfma_try(V a, V b, f4 c, long) {
  return __builtin_amdgcn_mfma_f32_16x16x32_bf16(
      __builtin_bit_cast(b8v, a), __builtin_bit_cast(b8v, b), c, 0, 0, 0);
}
__device__ inline f4 mfma_bf16(s8v a, s8v b, f4 c) { return mfma_try(a, b, c, 0); }

__device__ __forceinline__ unsigned short f2bf(float f) {
  unsigned u = __builtin_bit_cast(unsigned, f);
  u += 0x7FFFu + ((u >> 16) & 1u);   // RNE
  return (unsigned short)(u >> 16);
}
__device__ __forceinline__ float bf2f(unsigned short u) {
  return __builtin_bit_cast(float, (unsigned)u << 16);
}

// async global->LDS, 16B per lane; LDS dest is wave-uniform base + lane*16
#define GLOAD_LDS16(gp, lp)                                                   \
  __builtin_amdgcn_global_load_lds(                                           \
      (const __attribute__((address_space(1))) void*)(gp),                    \
      (__attribute__((address_space(3))) void*)(lp), 16, 0, 0)

// ---------------- fp32 -> bf16 cast, vectorized (G13): 8 floats/thread ------
__global__ void cast8_kernel(const float* __restrict__ in, unsigned short* __restrict__ out, int n8) {
  int i = blockIdx.x * blockDim.x + threadIdx.x;
  if (i < n8) {
    f4 a = ((const f4*)in)[i * 2];
    f4 b = ((const f4*)in)[i * 2 + 1];
    s8v o;
#pragma unroll
    for (int j = 0; j < 4; ++j) {
      o[j]     = (short)f2bf(a[j]);
      o[j + 4] = (short)f2bf(b[j]);
    }
    ((s8v*)out)[i] = o;
  }
}

// ---------------- ALL-layer weight prep in ONE dispatch ----------------
// Emits FRAGMENT-ORDERED bf16 weights: w[((nt*(K/8)+c)*16 + r)*8 + j] = W[c*8+j][nt*16+r]
__global__ void weight_prep_kernel(const float* __restrict__ Wq, const float* __restrict__ Wk,
                                   const float* __restrict__ Wv, const float* __restrict__ Wo_,
                                   const float* __restrict__ W1, const float* __restrict__ W2,
                                   const float* __restrict__ bq, const float* __restrict__ bk,
                                   const float* __restrict__ bv,
                                   unsigned short* __restrict__ wAll, float* __restrict__ bqkvAll) {
  int l = blockIdx.x / 3078;
  int id = blockIdx.x % 3078;
  unsigned short* wqkv = wAll + (size_t)l * WLYR;
  unsigned short* wo = wqkv + 3 * S1C;
  unsigned short* w1 = wo + S1C;
  unsigned short* w2 = w1 + S2C;
  if (id >= 3072) {   // bias concat
    int i = (id - 3072) * 256 + threadIdx.y * 32 + threadIdx.x;
    float* bqkv = bqkvAll + l * 1536;
    if (i < 512) bqkv[i] = bq[l * 512 + i];
    else if (i < 1024) bqkv[i] = bk[l * 512 + i - 512];
    else if (i < 1536) bqkv[i] = bv[l * 512 + i - 1024];
    return;
  }
  const float* in; unsigned short* out; int K, N, bx, by;
  if (id < 1024) {
    int m = id >> 8, t = id & 255;
    in = ((m == 0) ? Wq : (m == 1) ? Wk : (m == 2) ? Wv : Wo_) + (size_t)l * S1C;
    out = (m == 3) ? wo : wqkv + m * S1C;
    K = 512; N = 512; bx = t & 15; by = t >> 4;
  } else if (id < 2048) {
    int t = id - 1024;
    in = W1 + (size_t)l * S2C; out = w1; K = 512; N = 2048; bx = t & 63; by = t >> 6;
  } else {
    int t = id - 2048;
    in = W2 + (size_t)l * S2C; out = w2; K = 2048; N = 512; bx = t & 15; by = t >> 4;
  }
  __shared__ float t32[32][33];
  int tx = threadIdx.x, ty = threadIdx.y;
  int n0 = bx * 32, k0 = by * 32;
  int Kc = K >> 3;
#pragma unroll
  for (int i = 0; i < 32; i += 8)
    t32[ty + i][tx] = in[(size_t)(k0 + ty + i) * N + n0 + tx];
  __syncthreads();
#pragma unroll
  for (int i = 0; i < 32; i += 8) {
    int n = n0 + ty + i, k = k0 + tx;
    size_t idx = ((size_t)(n >> 4) * Kc + (k >> 3)) * 128 + (n & 15) * 8 + (k & 7);
    out[idx] = f2bf(t32[tx][ty + i]);   // t32[tx][ty+i] = W[k][n]
  }
}

// ---------------- GEMM 128x128: big-grid dispatches (QKV, FF1) ----------------
// ROUND-11 BEST CONFIG (1166.9us). GEMM micro-structure is a bracketed local
// optimum: 8-phase 256^2, BK=128, single-barrier dbuf, and double-K-tile all
// measured slower. SPLITB=true (launch_bounds(256,4)): s1-B loaded after s0
// MFMAs -> 32-VGPR peak B liveness -> 4 blocks/CU; wins at grids >= ~1024.
#define BM 128
#define BN 128
#define BK 64

template <bool OBF16, bool SPLITB>
__global__ __launch_bounds__(256, SPLITB ? 4 : 3) void gemm_bf16(
    const unsigned short* __restrict__ A, const unsigned short* __restrict__ Bt,
    const float* __restrict__ bias, void* __restrict__ Cp,
    int M, int K, int N, int relu) {
  __shared__ __align__(16) unsigned short As[8192];   // 128 x 64 bf16 (16 KB)
  int tid = threadIdx.x;
  int wave = tid >> 6, lane = tid & 63;
  int quad = lane >> 4, l16 = lane & 15;
  int wm = (wave >> 1) * 64, wn = (wave & 1) * 64;

  // XCD swizzle: contiguous work range per XCD
  int T = gridDim.x * gridDim.y;
  int i = blockIdx.y * gridDim.x + blockIdx.x;
  int C = T >> 3;
  int w = (i < (C << 3)) ? ((i & 7) * C + (i >> 3)) : i;
  int bx = w % gridDim.x, by = w / gridDim.x;
  int m0 = by * BM, n0 = bx * BN;

  f4 acc[4][4];
#pragma unroll
  for (int i2 = 0; i2 < 4; ++i2)
#pragma unroll
    for (int j = 0; j < 4; ++j) acc[i2][j] = (f4){0.f, 0.f, 0.f, 0.f};

  // A staging: round j covers rows [j*32, j*32+32); XOR-swizzled k-chunk
  int rbase = wave * 8 + (lane >> 3);
  int q8 = (lane & 7) ^ ((lane >> 3) & 7);
  const unsigned short* aptr[4];
#pragma unroll
  for (int j = 0; j < 4; ++j) {
    int r = j * 32 + rbase;
    int gm = m0 + r; if (gm >= M) gm = M - 1;   // clamp: dup rows never stored
    aptr[j] = A + (size_t)gm * K + q8 * 8;
  }

  // B fragment pointers: addr = (NT*(K/8) + c)*128 + l16*8, c = ks*8 + s*4 + quad
  int Kc = K >> 3;
  const unsigned short* bbase = Bt + quad * 128 + l16 * 8;
  size_t nioff[4];
#pragma unroll
  for (int i2 = 0; i2 < 4; ++i2)
    nioff[i2] = ((size_t)((n0 >> 4) + (wn >> 4) + i2) * Kc) * 128;

  int nk = K >> 6;
  for (int ks = 0; ks < nk; ++ks) {
#pragma unroll
    for (int j = 0; j < 4; ++j)
      GLOAD_LDS16(aptr[j], &As[j * 2048 + wave * 512]);

    if constexpr (SPLITB) {
      // s=0 B set only pre-barrier (32 VGPR peak B liveness)
      s8v bfr[4];
#pragma unroll
      for (int i2 = 0; i2 < 4; ++i2)
        bfr[i2] = *(const s8v*)(bbase + nioff[i2] + (size_t)ks * 1024);
#pragma unroll
      for (int j = 0; j < 4; ++j) aptr[j] += BK;
      __syncthreads();
      {
        s8v af[4];
#pragma unroll
        for (int i2 = 0; i2 < 4; ++i2) {
          int ra = wm + i2 * 16 + l16;
          af[i2] = *(const s8v*)(&As[ra * 64 + (((quad) ^ (ra & 7)) * 8)]);
        }
#pragma unroll
        for (int mi = 0; mi < 4; ++mi)
#pragma unroll
          for (int ni = 0; ni < 4; ++ni)
            acc[mi][ni] = mfma_bf16(af[mi], bfr[ni], acc[mi][ni]);
      }
#pragma unroll
      for (int i2 = 0; i2 < 4; ++i2)
        bfr[i2] = *(const s8v*)(bbase + nioff[i2] + (size_t)ks * 1024 + 512);
      {
        s8v af[4];
#pragma unroll
        for (int i2 = 0; i2 < 4; ++i2) {
          int ra = wm + i2 * 16 + l16;
          af[i2] = *(const s8v*)(&As[ra * 64 + (((4 | quad) ^ (ra & 7)) * 8)]);
        }
#pragma unroll
        for (int mi = 0; mi < 4; ++mi)
#pragma unroll
          for (int ni = 0; ni < 4; ++ni)
            acc[mi][ni] = mfma_bf16(af[mi], bfr[ni], acc[mi][ni]);
      }
      __syncthreads();
    } else {
      // round-1 verbatim: both B sets pre-barrier
      s8v bfr[2][4];
#pragma unroll
      for (int s = 0; s < 2; ++s)
#pragma unroll
        for (int i2 = 0; i2 < 4; ++i2)
          bfr[s][i2] = *(const s8v*)(bbase + nioff[i2] + (size_t)ks * 1024 + s * 512);
#pragma unroll
      for (int j = 0; j < 4; ++j) aptr[j] += BK;
      __syncthreads();
#pragma unroll
      for (int s = 0; s < 2; ++s) {
        s8v af[4];
#pragma unroll
        for (int i2 = 0; i2 < 4; ++i2) {
          int ra = wm + i2 * 16 + l16;
          af[i2] = *(const s8v*)(&As[ra * 64 + ((((s << 2) | quad) ^ (ra & 7)) * 8)]);
        }
#pragma unroll
        for (int mi = 0; mi < 4; ++mi)
#pragma unroll
          for (int ni = 0; ni < 4; ++ni)
            acc[mi][ni] = mfma_bf16(af[mi], bfr[s][ni], acc[mi][ni]);
      }
      __syncthreads();
    }
  }

  if constexpr (OBF16) {
    // coalesced bf16 epilogue: restage each wave's 16x64 subtile through LDS (reuse As)
    unsigned short* Cs = As + wave * 1088;   // 16 rows x 64 cols, stride 68
    float bvv[4];
#pragma unroll
    for (int ni = 0; ni < 4; ++ni) bvv[ni] = bias[n0 + wn + ni * 16 + l16];
    int row_l = lane >> 2, cg = lane & 3;
#pragma unroll
    for (int mi = 0; mi < 4; ++mi) {
#pragma unroll
      for (int ni = 0; ni < 4; ++ni) {
#pragma unroll
        for (int r = 0; r < 4; ++r) {
          float val = acc[mi][ni][r] + bvv[ni];
          if (relu) val = fmaxf(val, 0.f);
          Cs[(quad * 4 + r) * 68 + ni * 16 + l16] = f2bf(val);
        }
      }
      s8v v0 = *(const s8v*)(&Cs[row_l * 68 + cg * 16]);
      s8v v1 = *(const s8v*)(&Cs[row_l * 68 + cg * 16 + 8]);
      int grow = m0 + wm + mi * 16 + row_l;
      if (grow < M) {
        unsigned short* cp = (unsigned short*)Cp + (size_t)grow * N + n0 + wn + cg * 16;
        *(s8v*)cp = v0;
        *(s8v*)(cp + 8) = v1;
      }
    }
  } else {
#pragma unroll
    for (int ni = 0; ni < 4; ++ni) {
      int col = n0 + wn + ni * 16 + l16;
      float bv = bias[col];
#pragma unroll
      for (int mi = 0; mi < 4; ++mi) {
#pragma unroll
        for (int r = 0; r < 4; ++r) {
          int row = m0 + wm + mi * 16 + quad * 4 + r;
          if (row < M) {
            float val = acc[mi][ni][r] + bv;
            if (relu) val = fmaxf(val, 0.f);
            ((float*)Cp)[(size_t)row * N + col] = val;
          }
        }
      }
    }
  }
}

// ---------------- GEMM 64x128: small-grid dispatches (Wo, FF2) ----------------
// BM=64 doubles the small-N grid (1252 blocks) and fits 4 blocks/CU -- round-9's
// fix for the 2.45-blocks/CU drain-coverage hole (FF2 61 -> <57us measured).
__global__ __launch_bounds__(256, 4) void gemm_sm(
    const unsigned short* __restrict__ A, const unsigned short* __restrict__ Bt,
    const float* __restrict__ bias, unsigned short* __restrict__ Cp,
    int M, int K, int N, int relu) {
  __shared__ __align__(16) unsigned short As[4096];   // 64 x 64 bf16 (8 KB)
  int tid = threadIdx.x;
  int wave = tid >> 6, lane = tid & 63;
  int quad = lane >> 4, l16 = lane & 15;
  int wn = wave * 32;                 // wave covers 64 rows x 32 cols

  // XCD swizzle
  int T = gridDim.x * gridDim.y;
  int i = blockIdx.y * gridDim.x + blockIdx.x;
  int C = T >> 3;
  int w = (i < (C << 3)) ? ((i & 7) * C + (i >> 3)) : i;
  int bx = w % gridDim.x, by = w / gridDim.x;
  int m0 = by * 64, n0 = bx * BN;

  f4 acc[4][2];
#pragma unroll
  for (int i2 = 0; i2 < 4; ++i2)
#pragma unroll
    for (int j = 0; j < 2; ++j) acc[i2][j] = (f4){0.f, 0.f, 0.f, 0.f};

  // A staging: round j covers rows [j*32, j*32+32) (same pattern as 128-tile)
  int rbase = wave * 8 + (lane >> 3);
  int q8 = (lane & 7) ^ ((lane >> 3) & 7);
  const unsigned short* aptr[2];
#pragma unroll
  for (int j = 0; j < 2; ++j) {
    int r = j * 32 + rbase;
    int gm = m0 + r; if (gm >= M) gm = M - 1;
    aptr[j] = A + (size_t)gm * K + q8 * 8;
  }

  int Kc = K >> 3;
  const unsigned short* bbase = Bt + quad * 128 + l16 * 8;
  size_t nioff[2];
#pragma unroll
  for (int i2 = 0; i2 < 2; ++i2)
    nioff[i2] = ((size_t)((n0 >> 4) + (wn >> 4) + i2) * Kc) * 128;

  int nk = K >> 6;
  for (int ks = 0; ks < nk; ++ks) {
#pragma unroll
    for (int j = 0; j < 2; ++j)
      GLOAD_LDS16(aptr[j], &As[j * 2048 + wave * 512]);
    s8v bfr[2][2];
#pragma unroll
    for (int s = 0; s < 2; ++s)
#pragma unroll
      for (int i2 = 0; i2 < 2; ++i2)
        bfr[s][i2] = *(const s8v*)(bbase + nioff[i2] + (size_t)ks * 1024 + s * 512);
#pragma unroll
    for (int j = 0; j < 2; ++j) aptr[j] += BK;
    __syncthreads();
#pragma unroll
    for (int s = 0; s < 2; ++s) {
      s8v af[4];
#pragma unroll
      for (int i2 = 0; i2 < 4; ++i2) {
        int ra = i2 * 16 + l16;
        af[i2] = *(const s8v*)(&As[ra * 64 + ((((s << 2) | quad) ^ (ra & 7)) * 8)]);
      }
#pragma unroll
      for (int mi = 0; mi < 4; ++mi)
#pragma unroll
        for (int ni = 0; ni < 2; ++ni)
          acc[mi][ni] = mfma_bf16(af[mi], bfr[s][ni], acc[mi][ni]);
    }
    __syncthreads();
  }

  // bf16 epilogue: per-wave 16x32 restage (stride 36), coalesced s8v stores
  unsigned short* Cs = As + wave * 576;
  float bvv[2];
#pragma unroll
  for (int ni = 0; ni < 2; ++ni) bvv[ni] = bias[n0 + wn + ni * 16 + l16];
  int row_l = lane >> 2, cg = lane & 3;
#pragma unroll
  for (int mi = 0; mi < 4; ++mi) {
#pragma unroll
    for (int ni = 0; ni < 2; ++ni)
#pragma unroll
      for (int r = 0; r < 4; ++r) {
        float val = acc[mi][ni][r] + bvv[ni];
        if (relu) val = fmaxf(val, 0.f);
        Cs[(quad * 4 + r) * 36 + ni * 16 + l16] = f2bf(val);
      }
    s8v v0 = *(const s8v*)(&Cs[row_l * 36 + cg * 8]);
    int grow = m0 + mi * 16 + row_l;
    if (grow < M) {
      unsigned short* cp = Cp + (size_t)grow * N + n0 + wn + cg * 8;
      *(s8v*)cp = v0;
    }
  }
}

// ---------------- CSR build ----------------
__global__ void hist_kernel(const int* __restrict__ dst, int* __restrict__ cnt, int E) {
  int e = blockIdx.x * blockDim.x + threadIdx.x;
  if (e < E) atomicAdd(&cnt[dst[e]], 1);
}

// parallel two-level scan
__global__ void scan_blk_kernel(const int* __restrict__ cnt, int* __restrict__ incl,
                                int* __restrict__ bsum, int n) {
  __shared__ int sh[1024];
  int tid = threadIdx.x;
  int gi = blockIdx.x * 1024 + tid;
  int v = (gi < n) ? cnt[gi] : 0;
  sh[tid] = v;
  __syncthreads();
  for (int s = 1; s < 1024; s <<= 1) {
    int t = (tid >= s) ? sh[tid - s] : 0;
    __syncthreads();
    sh[tid] += t;
    __syncthreads();
  }
  if (gi < n) incl[gi] = sh[tid];
  if (tid == 1023) bsum[blockIdx.x] = sh[1023];
}

__global__ void scan_mid_kernel(const int* __restrict__ bsum, int* __restrict__ boff, int nb) {
  if (threadIdx.x == 0 && blockIdx.x == 0) {
    int run = 0;
    for (int i = 0; i < nb; ++i) { boff[i] = run; run += bsum[i]; }
    boff[nb] = run;
  }
}

__global__ void scan_fix_kernel(const int* __restrict__ incl, const int* __restrict__ boff,
                                int* __restrict__ offs, int n) {
  int gi = blockIdx.x * 1024 + threadIdx.x;
  if (gi < n) offs[gi + 1] = boff[blockIdx.x] + incl[gi];
  if (gi == 0) offs[0] = 0;
}

__global__ void scatter_kernel(const int* __restrict__ dst, const int* __restrict__ src,
                               const int* __restrict__ relations, const int* __restrict__ offs,
                               int* __restrict__ cursor, int* __restrict__ esrc,
                               int* __restrict__ erel, int E) {
  int e = blockIdx.x * blockDim.x + threadIdx.x;
  if (e < E) {
    int d = dst[e];
    int pos = offs[d] + atomicAdd(&cursor[d], 1);
    esrc[pos] = src[e];
    erel[pos] = relations[e];
  }
}

// ---------------- fused edge attention: one wave per dst node, online softmax -----
// 3-deep gather pipeline with lane-parallel index preload (perf-equal to simpler
// variants -> attn is gather-BW-bound on L3, near floor; kept as verified).
#define ATT_LOAD(j, kx, vx, rx) do {                                          \
    int sj = __shfl(si_l, (j), 64);                                           \
    int rj = __shfl(ri_l, (j), 64);                                           \
    kx = *(const s8v*)(k + (size_t)sj * STR + base);                          \
    vx = *(const s8v*)(v + (size_t)sj * STR + base);                          \
    rx = *(const s8v*)(relb + (size_t)rj * HIDDEN + base);                    \
  } while (0)

#define ATT_STEP(kc, vc, rc) do {                                             \
    float rf[8], p = 0.f;                                                     \
    _Pragma("unroll") for (int jj = 0; jj < 8; ++jj) {                        \
      rf[jj] = bf2f((unsigned short)kc[jj]);                                  \
      float rr = bf2f((unsigned short)rc[jj]);                                \
      p += (rf[jj] + rr) * qf[jj];                                            \
      rf[jj] = rr;                                                            \
    }                                                                         \
    p += __shfl_xor(p, 1, 64);                                                \
    p += __shfl_xor(p, 2, 64);                                                \
    p += __shfl_xor(p, 4, 64);                                                \
    p *= ATT_SCALE;                                                           \
    float mn = fmaxf(m, p);                                                   \
    float a = __expf(m - mn);                                                 \
    float wgt = __expf(p - mn);                                               \
    z = z * a + wgt;                                                          \
    _Pragma("unroll") for (int jj = 0; jj < 8; ++jj)                          \
      acc[jj] = acc[jj] * a + wgt * (bf2f((unsigned short)vc[jj]) + rf[jj]);  \
    m = mn;                                                                   \
  } while (0)

__global__ void edge_attn_kernel(const unsigned short* __restrict__ q,
                                 const unsigned short* __restrict__ k,
                                 const unsigned short* __restrict__ v,
                                 const unsigned short* __restrict__ relb,
                                 const int* __restrict__ offs,
                                 const int* __restrict__ esrc,
                                 const int* __restrict__ erel,
                                 unsigned short* __restrict__ o, int Nn, int STR) {
  int wid = (blockIdx.x * blockDim.x + threadIdx.x) >> 6;
  int lane = threadIdx.x & 63;
  if (wid >= Nn) return;
  int base = (lane >> 3) * HDK + (lane & 7) * 8;

  s8v qv = *(const s8v*)(q + (size_t)wid * STR + base);
  float qf[8];
#pragma unroll
  for (int j = 0; j < 8; ++j) qf[j] = bf2f((unsigned short)qv[j]);

  int beg = offs[wid], end = offs[wid + 1];
  float m = -1e30f, z = 0.f;
  float acc[8];
#pragma unroll
  for (int j = 0; j < 8; ++j) acc[j] = 0.f;

  for (int cbeg = beg; cbeg < end; cbeg += 64) {
    int cn = end - cbeg; if (cn > 64) cn = 64;
    int e = cbeg + lane;
    int si_l = 0, ri_l = 0;
    if (e < end) { si_l = esrc[e]; ri_l = erel[e]; }
    s8v kA = {}, vA = {}, rA = {};
    s8v kB = {}, vB = {}, rB = {};
    s8v kC = {}, vC = {}, rC = {};
    if (cn > 0) ATT_LOAD(0, kA, vA, rA);
    if (cn > 1) ATT_LOAD(1, kB, vB, rB);
    if (cn > 2) ATT_LOAD(2, kC, vC, rC);
    int j = 0;
    for (; j + 5 < cn; j += 3) {
      ATT_STEP(kA, vA, rA); ATT_LOAD(j + 3, kA, vA, rA);
      ATT_STEP(kB, vB, rB); ATT_LOAD(j + 4, kB, vB, rB);
      ATT_STEP(kC, vC, rC); ATT_LOAD(j + 5, kC, vC, rC);
    }
    int r = cn - j;   // 1..5
    if (r >= 1) ATT_STEP(kA, vA, rA);
    if (r >= 4) ATT_LOAD(j + 3, kA, vA, rA);
    if (r >= 2) ATT_STEP(kB, vB, rB);
    if (r >= 5) ATT_LOAD(j + 4, kB, vB, rB);
    if (r >= 3) ATT_STEP(kC, vC, rC);
    if (r >= 4) ATT_STEP(kA, vA, rA);
    if (r >= 5) ATT_STEP(kB, vB, rB);
  }

  float rz = 1.f / (z + 1e-9f);
  s8v ov;
#pragma unroll
  for (int j = 0; j < 8; ++j) ov[j] = (short)f2bf(acc[j] * rz);
  *(s8v*)(o + (size_t)wid * HIDDEN + base) = ov;
}

// ---------------- fused residual add + LayerNorm (one wave per row, bf16 in) ----------------
template <bool WF32>
__global__ void ln_kernel(const unsigned short* __restrict__ xp, const unsigned short* __restrict__ y,
                          const float* __restrict__ g, const float* __restrict__ b,
                          float* __restrict__ outf, unsigned short* __restrict__ outb, int Nn) {
  int wid = (blockIdx.x * blockDim.x + threadIdx.x) >> 6;
  int lane = threadIdx.x & 63;
  if (wid >= Nn) return;
  int base = lane * 8;
  s8v xv = *(const s8v*)(xp + (size_t)wid * HIDDEN + base);
  s8v yv = *(const s8v*)(y + (size_t)wid * HIDDEN + base);
  float vals[8];
  float sum = 0.f;
#pragma unroll
  for (int j = 0; j < 8; ++j) {
    vals[j] = bf2f((unsigned short)xv[j]) + bf2f((unsigned short)yv[j]);
    sum += vals[j];
  }
#pragma unroll
  for (int off = 32; off; off >>= 1) sum += __shfl_xor(sum, off, 64);
  float mean = sum * (1.f / 512.f);
  float sq = 0.f;
#pragma unroll
  for (int j = 0; j < 8; ++j) { float d = vals[j] - mean; sq += d * d; }
#pragma unroll
  for (int off = 32; off; off >>= 1) sq += __shfl_xor(sq, off, 64);
  float rstd = rsqrtf(sq * (1.f / 512.f) + 1e-5f);
  f4 gv0 = *(const f4*)(g + base);
  f4 gv1 = *(const f4*)(g + base + 4);
  f4 bv0 = *(const f4*)(b + base);
  f4 bv1 = *(const f4*)(b + base + 4);
  float ov_f[8];
#pragma unroll
  for (int j = 0; j < 4; ++j) {
    ov_f[j]     = (vals[j]     - mean) * rstd * gv0[j] + bv0[j];
    ov_f[j + 4] = (vals[j + 4] - mean) * rstd * gv1[j] + bv1[j];
  }
  s8v ov;
#pragma unroll
  for (int j = 0; j < 8; ++j) ov[j] = (short)f2bf(ov_f[j]);
  *(s8v*)(outb + (size_t)wid * HIDDEN + base) = ov;
  if constexpr (WF32) {
    f4 o0, o1;
#pragma unroll
    for (int j = 0; j < 4; ++j) { o0[j] = ov_f[j]; o1[j] = ov_f[j + 4]; }
    *(f4*)(outf + (size_t)wid * HIDDEN + base) = o0;
    *(f4*)(outf + (size_t)wid * HIDDEN + base + 4) = o1;
  }
}

// ---------------- host orchestration ----------------
extern "C" void kernel_launch(void* const* d_in, const int* in_sizes, int n_in,
                              void* d_out, int out_size, void* d_ws, size_t ws_size,
                              hipStream_t stream) {
  const float* x0        = (const float*)d_in[0];
  const int*   relations = (const int*)d_in[1];
  const int*   src       = (const int*)d_in[2];
  const int*   dst       = (const int*)d_in[3];
  const float* rel_embed = (const float*)d_in[4];
  const float* Wq = (const float*)d_in[5];  const float* bq = (const float*)d_in[6];
  const float* Wk = (const float*)d_in[7];  const float* bk = (const float*)d_in[8];
  const float* Wv = (const float*)d_in[9];  const float* bv = (const float*)d_in[10];
  const float* Wo = (const float*)d_in[11]; const float* bo = (const float*)d_in[12];
  const float* W1 = (const float*)d_in[13]; const float* b1 = (const float*)d_in[14];
  const float* W2 = (const float*)d_in[15]; const float* b2 = (const float*)d_in[16];
  const float* g1  = (const float*)d_in[17]; const float* bb1 = (const float*)d_in[18];
  const float* g2  = (const float*)d_in[19]; const float* bb2 = (const float*)d_in[20];
  float* xout = (float*)d_out;

  const size_t S1 = S1C;
  const size_t S2 = S2C;
  const size_t NH = (size_t)N_NODES * HIDDEN;   // 10,240,000

  // ---- workspace layout (~163 MiB) ----
  unsigned short* wAll = (unsigned short*)d_ws;           // 4 * WLYR bf16
  float* bqkvAll = (float*)(wAll + (size_t)NLAYER * WLYR); // 4*1536 fp32
  unsigned short* arena = (unsigned short*)(bqkvAll + NLAYER * 1536);  // 4*NH bf16
  unsigned short* qkvb = arena;                 // 3*NH, row stride 1536
  unsigned short* ob   = arena + 3 * NH;        // NH, row stride 512
  unsigned short* ff1  = arena;                 // 4*NH (qkv/ob dead by FF1 time)
  unsigned short* proj = arena;                 // NH bf16, aliases dead qkvb at Wo time
  unsigned short* hbb = arena + 4 * NH;         // NH bf16 (LN1 out)
  unsigned short* xb  = hbb + NH;               // NH bf16 (layer input / residual)
  unsigned short* projb = xb + NH;              // NH bf16 (FF2 out)
  unsigned short* relb  = projb + NH;           // 128*512 bf16
  int* cnt    = (int*)(relb + 65536);
  int* offs   = cnt + N_NODES;
  int* cursor = offs + N_NODES + 1;
  int* esrc   = cursor + N_NODES;
  int* erel   = esrc + N_EDGES;
  int* sincl  = erel + N_EDGES;     // 20480 (per-element inclusive scans)
  int* sbsum  = sincl + 20480;      // 32
  int* sboff  = sbsum + 32;         // 33

  // ---- setup (once per call) ----
  hipMemsetAsync(cnt, 0, N_NODES * sizeof(int), stream);
  hipMemsetAsync(cursor, 0, N_NODES * sizeof(int), stream);
  hist_kernel<<<(N_EDGES + 255) / 256, 256, 0, stream>>>(dst, cnt, N_EDGES);
  const int NB = (N_NODES + 1023) / 1024;   // 20
  scan_blk_kernel<<<NB, 1024, 0, stream>>>(cnt, sincl, sbsum, N_NODES);
  scan_mid_kernel<<<1, 64, 0, stream>>>(sbsum, sboff, NB);
  scan_fix_kernel<<<NB, 1024, 0, stream>>>(sincl, sboff, offs, N_NODES);
  scatter_kernel<<<(N_EDGES + 255) / 256, 256, 0, stream>>>(dst, src, relations, offs, cursor, esrc, erel, N_EDGES);
  cast8_kernel<<<(int)((NH / 8 + 255) / 256), 256, 0, stream>>>(x0, xb, (int)(NH / 8));
  cast8_kernel<<<32, 256, 0, stream>>>(rel_embed, relb, 8192);
  dim3 tb(32, 8);
  weight_prep_kernel<<<NLAYER * 3078, tb, 0, stream>>>(Wq, Wk, Wv, Wo, W1, W2, bq, bk, bv,
                                                       wAll, bqkvAll);

  const int MBc = (N_NODES + BM - 1) / BM;   // 157 (128-row tiles)
  const int MBs = (N_NODES + 63) / 64;       // 313 (64-row tiles)

  for (int l = 0; l < NLAYER; ++l) {
    unsigned short* wqkv = wAll + (size_t)l * WLYR;
    unsigned short* wo = wqkv + 3 * S1;
    unsigned short* w1 = wo + S1;
    unsigned short* w2 = w1 + S2;
    float* bqkv = bqkvAll + l * 1536;
    // merged QKV projection (big grid -> SPLITB)
    gemm_bf16<true, true><<<dim3(12, MBc), 256, 0, stream>>>(xb, wqkv, bqkv, qkvb, N_NODES, 512, 1536, 0);
    // fused edge attention
    edge_attn_kernel<<<(N_NODES + 3) / 4, 256, 0, stream>>>(qkvb, qkvb + 512, qkvb + 1024,
                                                            relb, offs, esrc, erel, ob, N_NODES, 1536);
    // output projection (small grid -> BM=64 high-occupancy kernel), then LN1
    gemm_sm<<<dim3(4, MBs), 256, 0, stream>>>(ob, wo, bo + l * 512, proj, N_NODES, 512, 512, 0);
    ln_kernel<false><<<N_NODES / 4, 256, 0, stream>>>(xb, proj, g1 + l * 512, bb1 + l * 512, nullptr, hbb, N_NODES);
    // FFN: FF1 big grid -> SPLITB; FF2 small grid -> BM=64 kernel
    gemm_bf16<true, true><<<dim3(16, MBc), 256, 0, stream>>>(hbb, w1, b1 + l * 2048, ff1, N_NODES, 512, 2048, 1);
    gemm_sm<<<dim3(4, MBs), 256, 0, stream>>>(ff1, w2, b2 + l * 512, projb, N_NODES, 2048, 512, 0);
    // LN2 -> xb (bf16 next-layer input/residual); final layer also writes fp32 xout
    if (l == NLAYER - 1)
      ln_kernel<true><<<N_NODES / 4, 256, 0, stream>>>(hbb, projb, g2 + l * 512, bb2 + l * 512, xout, xb, N_NODES);
    else
      ln_kernel<false><<<N_NODES / 4, 256, 0, stream>>>(hbb, projb, g2 + l * 512, bb2 + l * 512, nullptr, xb, N_NODES);
  }
}